// Round 5
// baseline (525.429 us; speedup 1.0000x reference)
//
#include <hip/hip_runtime.h>
#include <stdint.h>

#define BLK 256

constexpr int Bsz = 8, Ccls = 19, Hh = 512, Ww = 1024;
constexpr int Npix = Hh * Ww;          // 2^19
constexpr int TotPix = Bsz * Npix;     // 2^22
constexpr int NGroup = Bsz * Ccls;     // 152
constexpr int SUBS = 64;               // sub-histograms per image
constexpr int NB1 = 256;               // pass-1 bins (8-bit engineered key)
constexpr int NB2 = 4096;              // pass-2 bins (12 mantissa bits)
constexpr int KEY_BASE = 122 << 5;     // 3904: exponent 122 -> key 0
constexpr uint32_t LABM = 31u;         // low-5-bit label pack mask

// key1 = (u>>18) - 3904 : monotone in u, in [0,192) for max_prob in [1/19, 1]
__device__ __forceinline__ int key1_of(uint32_t u) {
  int k = (int)(u >> 18) - KEY_BASE;
  return k < 0 ? 0 : (k > 255 ? 255 : k);
}

// ---------------------------------------------------------------------------
// K1 (fused): max/argmax + softmax denom + pass-1 LDS histogram.
// 512 blocks: block = b*64 + s handles pixels [s*8192, (s+1)*8192) of image b.
// Output: packed u32 per pixel = (bits(max_prob) & ~31) | label.
//   - label fits in 5 bits (0..18); clearing 31 ulps of mp shifts -log(mp)
//     by ~4e-6 relative and cannot flip the topk compare (thresh low-6 = 0).
// Flush LDS hist (19x256 u32) non-atomically to h1[block][c][key]
// (atomics into a shared 156 KB region cost +27 us in R4 — do NOT merge).
// ---------------------------------------------------------------------------
__global__ __launch_bounds__(BLK) void k_fused(const float* __restrict__ pred,
                                               uint4* __restrict__ mp_out,
                                               uint32_t* __restrict__ h1) {
  __shared__ uint32_t hist[Ccls * NB1];
  int t = threadIdx.x;
#pragma unroll
  for (int c = 0; c < Ccls; ++c) hist[c * NB1 + t] = 0;
  __syncthreads();

  int blk = blockIdx.x;
  int b = blk >> 6;
  int s = blk & 63;
  const float* ibase = pred + (size_t)b * Ccls * Npix;
  int n0 = s * 8192;

  for (int j = 0; j < 8; ++j) {
    int n = n0 + j * 1024 + t * 4;
    float4 v[Ccls];
#pragma unroll
    for (int c = 0; c < Ccls; ++c)
      v[c] = *(const float4*)(ibase + (size_t)c * Npix + n);

    uint32_t pk[4];
#pragma unroll
    for (int q = 0; q < 4; ++q) {
      float m = ((const float*)&v[0])[q]; int l = 0;
#pragma unroll
      for (int c = 1; c < Ccls; ++c) {
        float x = ((const float*)&v[c])[q];
        if (x > m) { m = x; l = c; }
      }
      float sum = 0.f;
#pragma unroll
      for (int c = 0; c < Ccls; ++c) sum += __expf(((const float*)&v[c])[q] - m);
      float mp = 1.0f / sum;
      uint32_t u = __float_as_uint(mp);
      atomicAdd(&hist[l * NB1 + key1_of(u)], 1u);
      pk[q] = (u & ~LABM) | (uint32_t)l;
    }
    int p4 = b * (Npix / 4) + n / 4;
    mp_out[p4] = make_uint4(pk[0], pk[1], pk[2], pk[3]);
  }

  __syncthreads();
  uint32_t* dst = h1 + (size_t)blk * (Ccls * NB1);
#pragma unroll
  for (int c = 0; c < Ccls; ++c) dst[c * NB1 + t] = hist[c * NB1 + t];
}

// ---------------------------------------------------------------------------
// K2: per-group select over 256 bins (thread t owns bin 255-t, descending).
// Sums 64 sub-histograms (4-way ILP), scans, finds k-th bin + residual rank.
// ---------------------------------------------------------------------------
__global__ __launch_bounds__(BLK) void k_select1(const uint32_t* __restrict__ h1,
                                                 int* __restrict__ selhi,
                                                 int* __restrict__ rem) {
  int g = blockIdx.x;
  int b = g / Ccls, c = g % Ccls;
  int t = threadIdx.x;
  int bin = NB1 - 1 - t;
  const size_t gs = (size_t)Ccls * NB1;
  const uint32_t* hp = h1 + (size_t)(b * SUBS) * gs + c * NB1 + bin;
  uint32_t a0 = 0, a1 = 0, a2 = 0, a3 = 0;
  for (int s = 0; s < SUBS; s += 4) {
    a0 += hp[(size_t)(s + 0) * gs];
    a1 += hp[(size_t)(s + 1) * gs];
    a2 += hp[(size_t)(s + 2) * gs];
    a3 += hp[(size_t)(s + 3) * gs];
  }
  uint32_t cnt = a0 + a1 + a2 + a3;
  __shared__ uint32_t sc[BLK];
  sc[t] = cnt;
  __syncthreads();
  for (int ofs = 1; ofs < BLK; ofs <<= 1) {
    uint32_t vv = (t >= ofs) ? sc[t - ofs] : 0u;
    __syncthreads();
    sc[t] += vv;
    __syncthreads();
  }
  uint32_t incl = sc[t];
  uint32_t excl = incl - cnt;
  uint32_t total = sc[BLK - 1];
  int k = (int)((float)total * 0.66f);   // matches jnp f32 mul + trunc
  if (t == 0 && k == 0) { selhi[g] = -1; rem[g] = 0; }
  if (k > 0 && (int)excl < k && k <= (int)incl) {
    selhi[g] = bin;
    rem[g] = k - (int)excl;
  }
}

// ---------------------------------------------------------------------------
// K3: refined histogram — pixels whose key1 matches the selected bin get
// binned by mantissa bits [17:6]. ~500/group -> negligible atomic contention.
// ---------------------------------------------------------------------------
__global__ __launch_bounds__(BLK) void k_hist2(const uint4* __restrict__ mp,
                                               const int* __restrict__ selhi,
                                               uint32_t* __restrict__ hist2) {
  int p4 = blockIdx.x * BLK + threadIdx.x;
  int b = p4 >> 17;                       // / (Npix/4)
  uint4 m = mp[p4];
  const uint32_t* mu = (const uint32_t*)&m;
#pragma unroll
  for (int q = 0; q < 4; ++q) {
    uint32_t u = mu[q];
    int g = b * Ccls + (int)(u & LABM);
    if (key1_of(u) == selhi[g])
      atomicAdd(&hist2[g * NB2 + (int)((u >> 6) & 0xFFFu)], 1u);
  }
}

// ---------------------------------------------------------------------------
// K4: second select over 4096 bins (16 bins/thread, descending) -> threshold.
// thresh = bit-prefix such that mask_topk == (bits(mp) >= thresh).
// ---------------------------------------------------------------------------
__global__ __launch_bounds__(BLK) void k_select2(const uint32_t* __restrict__ hist2,
                                                 const int* __restrict__ selhi,
                                                 const int* __restrict__ rem,
                                                 uint32_t* __restrict__ thresh) {
  int g = blockIdx.x;
  int t = threadIdx.x;
  int sh = selhi[g];
  if (sh < 0) { if (t == 0) thresh[g] = 0x7F800000u; return; }
  const uint32_t* h = hist2 + g * NB2;
  uint32_t loc[16]; uint32_t psum = 0;
  int hi = NB2 - 1 - t * 16;
#pragma unroll
  for (int i = 0; i < 16; ++i) { loc[i] = h[hi - i]; psum += loc[i]; }
  __shared__ uint32_t sc[BLK];
  sc[t] = psum;
  __syncthreads();
  for (int ofs = 1; ofs < BLK; ofs <<= 1) {
    uint32_t vv = (t >= ofs) ? sc[t - ofs] : 0u;
    __syncthreads();
    sc[t] += vv;
    __syncthreads();
  }
  uint32_t incl = sc[t];
  int k = rem[g];
  uint32_t excl = incl - psum;
  if (k > 0 && (int)excl < k && k <= (int)incl) {
    uint32_t cum = excl;
#pragma unroll
    for (int i = 0; i < 16; ++i) {
      if ((uint32_t)k <= cum + loc[i]) {
        thresh[g] = ((uint32_t)(sh + KEY_BASE) << 18) | ((uint32_t)(hi - i) << 6);
        break;
      }
      cum += loc[i];
    }
  }
}

// ---------------------------------------------------------------------------
// K5: masked reduction: sum(-log(mp)) and count. nll(pseudo) == -log(max_prob).
// Last block (device-scope ticket, verified in R4) writes the final scalar.
// ---------------------------------------------------------------------------
__global__ __launch_bounds__(BLK) void k_loss(const uint4* __restrict__ mp_arr,
                                              const uint32_t* __restrict__ thresh,
                                              float* __restrict__ gsum,
                                              uint32_t* __restrict__ gcnt,
                                              uint32_t* __restrict__ gdone,
                                              float* __restrict__ out) {
  int p4 = blockIdx.x * BLK + threadIdx.x;
  int b = p4 >> 17;
  uint4 m = mp_arr[p4];
  const uint32_t* mu = (const uint32_t*)&m;
  float vs = 0.f; uint32_t vc = 0u;
#pragma unroll
  for (int q = 0; q < 4; ++q) {
    uint32_t u = mu[q];
    int g = b * Ccls + (int)(u & LABM);
    float mp = __uint_as_float(u & ~LABM);
    bool sel = (mp > 0.9f) || ((u & ~LABM) >= thresh[g]);
    if (sel) { vs += -logf(mp); vc += 1u; }
  }
#pragma unroll
  for (int o = 32; o > 0; o >>= 1) {
    vs += __shfl_down(vs, o, 64);
    vc += __shfl_down(vc, o, 64);
  }
  __shared__ float ssum[BLK / 64];
  __shared__ uint32_t scnt[BLK / 64];
  int wave = threadIdx.x >> 6;
  int lane = threadIdx.x & 63;
  if (lane == 0) { ssum[wave] = vs; scnt[wave] = vc; }
  __syncthreads();
  if (threadIdx.x == 0) {
    float ts = 0.f; uint32_t tc = 0u;
#pragma unroll
    for (int w = 0; w < BLK / 64; ++w) { ts += ssum[w]; tc += scnt[w]; }
    atomicAdd(gsum, ts);
    atomicAdd(gcnt, tc);
    __threadfence();                       // order our adds before the ticket
    uint32_t ticket = atomicAdd(gdone, 1u);
    if (ticket == gridDim.x - 1) {
      float    sv = atomicAdd(gsum, 0.0f); // atomic RMW read: device-coherent
      uint32_t cv = atomicAdd(gcnt, 0u);
      out[0] = sv / (float)(cv > 0u ? cv : 1u);
    }
  }
}

// ---------------------------------------------------------------------------
extern "C" void kernel_launch(void* const* d_in, const int* in_sizes, int n_in,
                              void* d_out, int out_size, void* d_ws, size_t ws_size,
                              hipStream_t stream) {
  const float* pred = (const float*)d_in[0];
  char* ws = (char*)d_ws;
  size_t off = 0;
  auto carve = [&](size_t bytes) -> void* {
    void* p = ws + off;
    off = (off + bytes + 255) & ~(size_t)255;
    return p;
  };
  uint32_t* mp    = (uint32_t*)carve((size_t)TotPix * 4);              // packed mp|lab
  uint32_t* h1    = (uint32_t*)carve((size_t)Bsz * SUBS * Ccls * NB1 * 4); // ~10 MB, fully written
  int*      selhi = (int*)carve((size_t)NGroup * 4);
  int*      rem   = (int*)carve((size_t)NGroup * 4);
  uint32_t* thr   = (uint32_t*)carve((size_t)NGroup * 4);
  size_t zero_off = off;                 // memset region: hist2 + scalars
  uint32_t* hist2 = (uint32_t*)carve((size_t)NGroup * NB2 * 4);
  float*    gsum  = (float*)carve(4);
  uint32_t* gcnt  = (uint32_t*)carve(4);
  uint32_t* gdone = (uint32_t*)carve(4);

  hipMemsetAsync(ws + zero_off, 0, off - zero_off, stream);

  int nblk4 = TotPix / (BLK * 4);        // 4096
  k_fused  <<<Bsz * SUBS, BLK, 0, stream>>>(pred, (uint4*)mp, h1);
  k_select1<<<NGroup,     BLK, 0, stream>>>(h1, selhi, rem);
  k_hist2  <<<nblk4,      BLK, 0, stream>>>((const uint4*)mp, selhi, hist2);
  k_select2<<<NGroup,     BLK, 0, stream>>>(hist2, selhi, rem, thr);
  k_loss   <<<nblk4,      BLK, 0, stream>>>((const uint4*)mp, thr,
                                            gsum, gcnt, gdone, (float*)d_out);
}

// Round 7
// 493.519 us; speedup vs baseline: 1.0647x; 1.0647x over previous
//
#include <hip/hip_runtime.h>
#include <stdint.h>

#define BLK 256

constexpr int Bsz = 8, Ccls = 19, Hh = 512, Ww = 1024;
constexpr int Npix = Hh * Ww;          // 2^19
constexpr int TotPix = Bsz * Npix;     // 2^22
constexpr int NGroup = Bsz * Ccls;     // 152
constexpr int SUBS = 64;               // sub-histograms per image
constexpr int NB1 = 256;               // pass-1 bins (8-bit engineered key)
constexpr int NB2 = 4096;              // pass-2 bins (12 mantissa bits)
constexpr int KEY_BASE = 122 << 5;     // 3904: exponent 122 -> key 0
constexpr uint32_t LABM = 31u;         // low-5-bit label pack mask

// key1 = (u>>18) - 3904 : monotone in u, in [0,192) for max_prob in [1/19, 1]
__device__ __forceinline__ int key1_of(uint32_t u) {
  int k = (int)(u >> 18) - KEY_BASE;
  return k < 0 ? 0 : (k > 255 ? 255 : k);
}

// ---------------------------------------------------------------------------
// K1 (fused): max/argmax + softmax denom + pass-1 LDS histogram.
// 512 blocks: block = b*64 + s handles pixels [s*8192, (s+1)*8192) of image b.
// Output: packed u32 per pixel = (bits(max_prob) & ~31) | label.
// Flush LDS hist (19x256 u32) non-atomically to h1[block][c][key].
// NOTES from A/B history: global-atomic h1 merge = +0 (R4/R5 diff), per-block
// device threadfence ticket = +25 us (R4+R5) -> both reverted/avoided.
// ---------------------------------------------------------------------------
__global__ __launch_bounds__(BLK) void k_fused(const float* __restrict__ pred,
                                               uint4* __restrict__ mp_out,
                                               uint32_t* __restrict__ h1) {
  __shared__ uint32_t hist[Ccls * NB1];
  int t = threadIdx.x;
#pragma unroll
  for (int c = 0; c < Ccls; ++c) hist[c * NB1 + t] = 0;
  __syncthreads();

  int blk = blockIdx.x;
  int b = blk >> 6;
  int s = blk & 63;
  const float* ibase = pred + (size_t)b * Ccls * Npix;
  int n0 = s * 8192;

  for (int j = 0; j < 8; ++j) {
    int n = n0 + j * 1024 + t * 4;
    float4 v[Ccls];
#pragma unroll
    for (int c = 0; c < Ccls; ++c)
      v[c] = *(const float4*)(ibase + (size_t)c * Npix + n);

    uint32_t pk[4];
#pragma unroll
    for (int q = 0; q < 4; ++q) {
      float m = ((const float*)&v[0])[q]; int l = 0;
#pragma unroll
      for (int c = 1; c < Ccls; ++c) {
        float x = ((const float*)&v[c])[q];
        if (x > m) { m = x; l = c; }
      }
      float sum = 0.f;
#pragma unroll
      for (int c = 0; c < Ccls; ++c) sum += __expf(((const float*)&v[c])[q] - m);
      float mp = 1.0f / sum;
      uint32_t u = __float_as_uint(mp);
      atomicAdd(&hist[l * NB1 + key1_of(u)], 1u);
      pk[q] = (u & ~LABM) | (uint32_t)l;
    }
    int p4 = b * (Npix / 4) + n / 4;
    mp_out[p4] = make_uint4(pk[0], pk[1], pk[2], pk[3]);
  }

  __syncthreads();
  uint32_t* dst = h1 + (size_t)blk * (Ccls * NB1);
#pragma unroll
  for (int c = 0; c < Ccls; ++c) dst[c * NB1 + t] = hist[c * NB1 + t];
}

// ---------------------------------------------------------------------------
// K2: per-group select over 256 bins (thread t owns bin 255-t, descending).
// Sums 64 sub-histograms (4-way ILP), scans, finds k-th bin + residual rank.
// ---------------------------------------------------------------------------
__global__ __launch_bounds__(BLK) void k_select1(const uint32_t* __restrict__ h1,
                                                 int* __restrict__ selhi,
                                                 int* __restrict__ rem) {
  int g = blockIdx.x;
  int b = g / Ccls, c = g % Ccls;
  int t = threadIdx.x;
  int bin = NB1 - 1 - t;
  const size_t gs = (size_t)Ccls * NB1;
  const uint32_t* hp = h1 + (size_t)(b * SUBS) * gs + c * NB1 + bin;
  uint32_t a0 = 0, a1 = 0, a2 = 0, a3 = 0;
  for (int s = 0; s < SUBS; s += 4) {
    a0 += hp[(size_t)(s + 0) * gs];
    a1 += hp[(size_t)(s + 1) * gs];
    a2 += hp[(size_t)(s + 2) * gs];
    a3 += hp[(size_t)(s + 3) * gs];
  }
  uint32_t cnt = a0 + a1 + a2 + a3;
  __shared__ uint32_t sc[BLK];
  sc[t] = cnt;
  __syncthreads();
  for (int ofs = 1; ofs < BLK; ofs <<= 1) {
    uint32_t vv = (t >= ofs) ? sc[t - ofs] : 0u;
    __syncthreads();
    sc[t] += vv;
    __syncthreads();
  }
  uint32_t incl = sc[t];
  uint32_t excl = incl - cnt;
  uint32_t total = sc[BLK - 1];
  int k = (int)((float)total * 0.66f);   // matches jnp f32 mul + trunc
  if (t == 0 && k == 0) { selhi[g] = -1; rem[g] = 0; }
  if (k > 0 && (int)excl < k && k <= (int)incl) {
    selhi[g] = bin;
    rem[g] = k - (int)excl;
  }
}

// ---------------------------------------------------------------------------
// K3: refined histogram — pixels whose key1 matches the selected bin get
// binned by mantissa bits [17:6]. ~500/group -> negligible atomic contention.
// ---------------------------------------------------------------------------
__global__ __launch_bounds__(BLK) void k_hist2(const uint4* __restrict__ mp,
                                               const int* __restrict__ selhi,
                                               uint32_t* __restrict__ hist2) {
  int p4 = blockIdx.x * BLK + threadIdx.x;
  int b = p4 >> 17;                       // / (Npix/4)
  uint4 m = mp[p4];
  const uint32_t* mu = (const uint32_t*)&m;
#pragma unroll
  for (int q = 0; q < 4; ++q) {
    uint32_t u = mu[q];
    int g = b * Ccls + (int)(u & LABM);
    if (key1_of(u) == selhi[g])
      atomicAdd(&hist2[g * NB2 + (int)((u >> 6) & 0xFFFu)], 1u);
  }
}

// ---------------------------------------------------------------------------
// K4: second select over 4096 bins (16 bins/thread, descending) -> threshold.
// thresh = bit-prefix such that mask_topk == (bits(mp) >= thresh).
// ---------------------------------------------------------------------------
__global__ __launch_bounds__(BLK) void k_select2(const uint32_t* __restrict__ hist2,
                                                 const int* __restrict__ selhi,
                                                 const int* __restrict__ rem,
                                                 uint32_t* __restrict__ thresh) {
  int g = blockIdx.x;
  int t = threadIdx.x;
  int sh = selhi[g];
  if (sh < 0) { if (t == 0) thresh[g] = 0x7F800000u; return; }
  const uint32_t* h = hist2 + g * NB2;
  uint32_t loc[16]; uint32_t psum = 0;
  int hi = NB2 - 1 - t * 16;
#pragma unroll
  for (int i = 0; i < 16; ++i) { loc[i] = h[hi - i]; psum += loc[i]; }
  __shared__ uint32_t sc[BLK];
  sc[t] = psum;
  __syncthreads();
  for (int ofs = 1; ofs < BLK; ofs <<= 1) {
    uint32_t vv = (t >= ofs) ? sc[t - ofs] : 0u;
    __syncthreads();
    sc[t] += vv;
    __syncthreads();
  }
  uint32_t incl = sc[t];
  int k = rem[g];
  uint32_t excl = incl - psum;
  if (k > 0 && (int)excl < k && k <= (int)incl) {
    uint32_t cum = excl;
#pragma unroll
    for (int i = 0; i < 16; ++i) {
      if ((uint32_t)k <= cum + loc[i]) {
        thresh[g] = ((uint32_t)(sh + KEY_BASE) << 18) | ((uint32_t)(hi - i) << 6);
        break;
      }
      cum += loc[i];
    }
  }
}

// ---------------------------------------------------------------------------
// K5: masked reduction: sum(-log(mp)) and count. nll(pseudo) == -log(max_prob).
// Plain per-block atomics only; final division in a separate 1-thread kernel
// (per-block device-scope fence ticket measured +25 us on 8-XCD MI355X).
// ---------------------------------------------------------------------------
__global__ __launch_bounds__(BLK) void k_loss(const uint4* __restrict__ mp_arr,
                                              const uint32_t* __restrict__ thresh,
                                              float* __restrict__ gsum,
                                              uint32_t* __restrict__ gcnt) {
  int p4 = blockIdx.x * BLK + threadIdx.x;
  int b = p4 >> 17;
  uint4 m = mp_arr[p4];
  const uint32_t* mu = (const uint32_t*)&m;
  float vs = 0.f; uint32_t vc = 0u;
#pragma unroll
  for (int q = 0; q < 4; ++q) {
    uint32_t u = mu[q];
    int g = b * Ccls + (int)(u & LABM);
    uint32_t ub = u & ~LABM;
    float mp = __uint_as_float(ub);
    bool sel = (mp > 0.9f) || (ub >= thresh[g]);
    if (sel) { vs += -__logf(mp); vc += 1u; }
  }
#pragma unroll
  for (int o = 32; o > 0; o >>= 1) {
    vs += __shfl_down(vs, o, 64);
    vc += __shfl_down(vc, o, 64);
  }
  __shared__ float ssum[BLK / 64];
  __shared__ uint32_t scnt[BLK / 64];
  int wave = threadIdx.x >> 6;
  int lane = threadIdx.x & 63;
  if (lane == 0) { ssum[wave] = vs; scnt[wave] = vc; }
  __syncthreads();
  if (threadIdx.x == 0) {
    float ts = 0.f; uint32_t tc = 0u;
#pragma unroll
    for (int w = 0; w < BLK / 64; ++w) { ts += ssum[w]; tc += scnt[w]; }
    atomicAdd(gsum, ts);
    atomicAdd(gcnt, tc);
  }
}

__global__ void k_final(const float* __restrict__ gsum,
                        const uint32_t* __restrict__ gcnt,
                        float* __restrict__ out) {
  uint32_t c = *gcnt;
  float d = (float)(c > 0u ? c : 1u);
  out[0] = *gsum / d;
}

// ---------------------------------------------------------------------------
extern "C" void kernel_launch(void* const* d_in, const int* in_sizes, int n_in,
                              void* d_out, int out_size, void* d_ws, size_t ws_size,
                              hipStream_t stream) {
  const float* pred = (const float*)d_in[0];
  char* ws = (char*)d_ws;
  size_t off = 0;
  auto carve = [&](size_t bytes) -> void* {
    void* p = ws + off;
    off = (off + bytes + 255) & ~(size_t)255;
    return p;
  };
  uint32_t* mp    = (uint32_t*)carve((size_t)TotPix * 4);                  // packed mp|lab
  uint32_t* h1    = (uint32_t*)carve((size_t)Bsz * SUBS * Ccls * NB1 * 4); // ~10 MB, fully written
  int*      selhi = (int*)carve((size_t)NGroup * 4);
  int*      rem   = (int*)carve((size_t)NGroup * 4);
  uint32_t* thr   = (uint32_t*)carve((size_t)NGroup * 4);
  size_t zero_off = off;                 // memset region: hist2 + gsum + gcnt
  uint32_t* hist2 = (uint32_t*)carve((size_t)NGroup * NB2 * 4);
  float*    gsum  = (float*)carve(4);
  uint32_t* gcnt  = (uint32_t*)carve(4);

  hipMemsetAsync(ws + zero_off, 0, off - zero_off, stream);

  int nblk4 = TotPix / (BLK * 4);        // 4096
  k_fused  <<<Bsz * SUBS, BLK, 0, stream>>>(pred, (uint4*)mp, h1);
  k_select1<<<NGroup,     BLK, 0, stream>>>(h1, selhi, rem);
  k_hist2  <<<nblk4,      BLK, 0, stream>>>((const uint4*)mp, selhi, hist2);
  k_select2<<<NGroup,     BLK, 0, stream>>>(hist2, selhi, rem, thr);
  k_loss   <<<nblk4,      BLK, 0, stream>>>((const uint4*)mp, thr, gsum, gcnt);
  k_final  <<<1, 1, 0, stream>>>(gsum, gcnt, (float*)d_out);
}